// Round 3
// baseline (1355.425 us; speedup 1.0000x reference)
//
#include <hip/hip_runtime.h>
#include <stdint.h>

#pragma clang fp contract(off)   // match numpy: no FMA fusion in decode/IoU math

static constexpr int TOPK  = 5000;
static constexpr int KEEPK = 750;
static constexpr int MPAD  = 65536;   // >= N (33600), power of 2
static constexpr int NBLK  = (TOPK + 63) / 64;   // 79
static constexpr int KROW  = NBLK * 64;          // 5056 (padded mask row)
static constexpr float TH  = 0.3f;    // strict '>' everywhere (f32 weak-typed 0.3)

__device__ __forceinline__ uint32_t key_of(float f) {
  uint32_t u = __float_as_uint(f);
  u = (u & 0x80000000u) ? ~u : (u | 0x80000000u);  // ascending-ordered uint
  return ~u;                                        // ascending key == descending float
}
__device__ __forceinline__ float val_of(uint32_t key) {
  uint32_t u = ~key;
  return (u & 0x80000000u) ? __uint_as_float(u ^ 0x80000000u) : __uint_as_float(~u);
}

// ---------------- stage 1: composite keys (score desc, index asc) ----------------
__global__ void build_keys(const float* __restrict__ cls, const float* __restrict__ obj,
                           uint64_t* __restrict__ keys, int N) {
  int b = blockIdx.y;
  int i = blockIdx.x * blockDim.x + threadIdx.x;
  if (i >= MPAD) return;
  uint64_t c = ~0ull;
  if (i < N) {
    size_t o = (size_t)b * N + i;
    float s = sqrtf(cls[o] * obj[o]);          // mul+sqrt: bit-exact vs np
    float m = (s > TH) ? s : -1.0f;            // strict > (jax weak-typed f32 0.3)
    c = ((uint64_t)key_of(m) << 32) | (uint32_t)i;
  }
  keys[(size_t)b * MPAD + i] = c;
}

// ---------------- bitonic sort (ascending) over MPAD per batch ----------------
__global__ __launch_bounds__(1024) void bitonic_local_full(uint64_t* __restrict__ keys) {
  __shared__ uint64_t sh[8192];
  int base = blockIdx.x * 8192;
  uint64_t* a = keys + (size_t)blockIdx.y * MPAD + base;
  for (int t = threadIdx.x; t < 8192; t += 1024) sh[t] = a[t];
  __syncthreads();
  for (int k = 2; k <= 8192; k <<= 1) {
    for (int j = k >> 1; j > 0; j >>= 1) {
      for (int t = threadIdx.x; t < 4096; t += 1024) {
        int i = ((t & ~(j - 1)) << 1) | (t & (j - 1));
        int l = i | j;
        bool asc = (((base + i) & k) == 0);
        uint64_t x = sh[i], y = sh[l];
        if ((x > y) == asc) { sh[i] = y; sh[l] = x; }
      }
      __syncthreads();
    }
  }
  for (int t = threadIdx.x; t < 8192; t += 1024) a[t] = sh[t];
}

__global__ void bitonic_global_pass(uint64_t* __restrict__ keys, int k, int j) {
  int b = blockIdx.y;
  int t = blockIdx.x * blockDim.x + threadIdx.x;  // t < MPAD/2
  uint64_t* a = keys + (size_t)b * MPAD;
  int i = ((t & ~(j - 1)) << 1) | (t & (j - 1));
  int l = i | j;
  bool asc = ((i & k) == 0);
  uint64_t x = a[i], y = a[l];
  if ((x > y) == asc) { a[i] = y; a[l] = x; }
}

__global__ __launch_bounds__(1024) void bitonic_local_finish(uint64_t* __restrict__ keys, int k) {
  __shared__ uint64_t sh[8192];
  int base = blockIdx.x * 8192;
  uint64_t* a = keys + (size_t)blockIdx.y * MPAD + base;
  for (int t = threadIdx.x; t < 8192; t += 1024) sh[t] = a[t];
  __syncthreads();
  for (int j = 4096; j > 0; j >>= 1) {
    for (int t = threadIdx.x; t < 4096; t += 1024) {
      int i = ((t & ~(j - 1)) << 1) | (t & (j - 1));
      int l = i | j;
      bool asc = (((base + i) & k) == 0);
      uint64_t x = sh[i], y = sh[l];
      if ((x > y) == asc) { sh[i] = y; sh[l] = x; }
    }
    __syncthreads();
  }
  for (int t = threadIdx.x; t < 8192; t += 1024) a[t] = sh[t];
}

// ---------------- stage 2: gather top-5000, decode boxes+kps ----------------
__global__ void gather_decode(const uint64_t* __restrict__ keys,
                              const float* __restrict__ bbox, const float* __restrict__ kps,
                              const float* __restrict__ priors,
                              float* __restrict__ dets, float* __restrict__ tscore, int N) {
  int b = blockIdx.y;
  int r = blockIdx.x * blockDim.x + threadIdx.x;
  if (r >= TOPK) return;
  uint64_t c = keys[(size_t)b * MPAD + r];
  uint32_t idx = (uint32_t)c;
  float score = val_of((uint32_t)(c >> 32));
  float4 pr = ((const float4*)priors)[idx];
  const float* bb = bbox + ((size_t)b * N + idx) * 4;
  float cx = pr.x + bb[0] * pr.z;
  float cy = pr.y + bb[1] * pr.w;
  float w = pr.z * expf(bb[2]);
  float h = pr.w * expf(bb[3]);
  float x1 = cx - w * 0.5f, y1 = cy - h * 0.5f;
  float* d = dets + ((size_t)b * TOPK + r) * 16;
  d[0] = x1; d[1] = y1; d[2] = x1 + w; d[3] = y1 + h;
  const float* kp = kps + ((size_t)b * N + idx) * 10;
#pragma unroll
  for (int q = 0; q < 5; ++q) {
    d[4 + 2 * q] = pr.x + kp[2 * q] * pr.z;
    d[5 + 2 * q] = pr.y + kp[2 * q + 1] * pr.w;
  }
  d[14] = score;
  tscore[(size_t)b * TOPK + r] = score;
}

// ---------------- stage 3: NMS suppression bitmask (upper triangle) ----------------
__global__ __launch_bounds__(64) void nms_mask(const float* __restrict__ dets,
                                               uint64_t* __restrict__ mask) {
  int ib = blockIdx.x, jb = blockIdx.y, b = blockIdx.z;
  if (jb < ib) return;
  __shared__ float4 jbox[64];
  int t = threadIdx.x;
  int j0 = jb * 64;
  {
    int j = j0 + t;
    if (j < TOPK) {
      const float* dj = dets + ((size_t)b * TOPK + j) * 16;
      jbox[t] = make_float4(dj[0], dj[1], dj[2], dj[3]);
    } else jbox[t] = make_float4(0.f, 0.f, 0.f, 0.f);
  }
  __syncthreads();
  int i = ib * 64 + t;
  uint64_t bits = 0;
  if (i < TOPK) {
    const float* di = dets + ((size_t)b * TOPK + i) * 16;
    float ix1 = di[0], iy1 = di[1], ix2 = di[2], iy2 = di[3];
    float iar = fmaxf(ix2 - ix1, 0.f) * fmaxf(iy2 - iy1, 0.f);
    int jmax = min(64, TOPK - j0);
    for (int u = 0; u < jmax; ++u) {
      int j = j0 + u;
      if (j <= i) continue;
      float4 bx = jbox[u];
      float xx1 = fmaxf(ix1, bx.x), yy1 = fmaxf(iy1, bx.y);
      float xx2 = fminf(ix2, bx.z), yy2 = fminf(iy2, bx.w);
      float ww = fmaxf(xx2 - xx1, 0.f), hh = fmaxf(yy2 - yy1, 0.f);
      float inter = ww * hh;
      float jar = fmaxf(bx.z - bx.x, 0.f) * fmaxf(bx.w - bx.y, 0.f);
      float iou = inter / (iar + jar - inter + 1e-12f);
      if (iou > TH) bits |= (1ull << u);       // strict > (f32 0.3)
    }
  }
  mask[((size_t)b * NBLK + jb) * KROW + (size_t)(ib * 64 + t)] = bits;
}

// ---------------- stage 4+5: greedy scan (gather form) + fused top-750 emit ----------------
// One wave per batch. remv[bi] is GATHERED at chunk bi (coalesced row-prefix reads,
// all loads independent -> pipelined), instead of scattered forward (which the
// compiler serialized to 1 outstanding load @ VGPR_Count=20 -> 23k cyc/chunk).
__global__ __launch_bounds__(64) void nms_scan_emit(const uint64_t* __restrict__ mask,
                                                    const float* __restrict__ tscore,
                                                    const float* __restrict__ dets,
                                                    float* __restrict__ out, int B) {
  int b = blockIdx.x;
  int lane = threadIdx.x;
  __shared__ uint64_t s_alive[NBLK];
  __shared__ int s_pref[NBLK + 1];
  const uint64_t* mb = mask + (size_t)b * NBLK * KROW;
  const float* sb = tscore + (size_t)b * TOPK;

  for (int bi = 0; bi < NBLK; ++bi) {
    const uint64_t* rowb = mb + (size_t)bi * KROW;
    // gather: remv word for chunk bi = OR over alive items in prior chunks
    uint64_t acc = 0;
#pragma unroll 8
    for (int cb = 0; cb < bi; ++cb) {
      uint64_t a = s_alive[cb];                 // LDS broadcast
      uint64_t m = rowb[cb * 64 + lane];        // coalesced 512B wave-load
      acc |= (((a >> lane) & 1ull) ? m : 0ull);
    }
#pragma unroll
    for (int off = 32; off; off >>= 1)
      acc |= (uint64_t)__shfl_xor((unsigned long long)acc, off, 64);
    uint64_t w = acc;                            // uniform across wave

    int p = bi * 64 + lane;
    float s = (p < TOPK) ? sb[p] : -1.0f;        // coalesced
    uint64_t valid = __ballot(s > TH);           // uniform
    uint64_t diag = rowb[(size_t)bi * 64 + lane];// diagonal block, coalesced

    // in-register serial closure over 64 items (4 groups of 16 pre-extracted words)
    uint64_t alive = 0;
#pragma unroll
    for (int g = 0; g < 4; ++g) {
      uint64_t mreg[16];
#pragma unroll
      for (int t = 0; t < 16; ++t)
        mreg[t] = (uint64_t)__shfl((unsigned long long)diag, g * 16 + t, 64);
#pragma unroll
      for (int t = 0; t < 16; ++t) {
        uint64_t bit = 1ull << (g * 16 + t);
        bool live = ((valid & bit) != 0) && ((w & bit) == 0);
        if (live) { alive |= bit; w |= mreg[t]; }
      }
    }
    if (lane == 0) s_alive[bi] = alive;
    __syncthreads();
  }

  // prefix sums of kept counts per chunk
  if (lane == 0) {
    int run = 0;
    for (int cb = 0; cb < NBLK; ++cb) { s_pref[cb] = run; run += __popcll(s_alive[cb]); }
    s_pref[NBLK] = run;
  }
  __syncthreads();
  int K = s_pref[NBLK];

  // top-750 of where(keep, score, -1) == [kept in position order] ++ [not-kept in
  // position order]  (tscore already desc with index-asc ties; -1 ties -> index asc)
  for (int cb = 0; cb < NBLK; ++cb) {
    int p = cb * 64 + lane;
    if (p >= TOPK) continue;
    uint64_t aw = s_alive[cb];
    int kept = (int)((aw >> lane) & 1ull);
    int within = __popcll(aw & ((1ull << lane) - 1ull));
    int rank = s_pref[cb] + within;                       // kept rank
    int slot = kept ? rank : (K + (p - s_pref[cb] - within));  // filler after all kept
    if (slot < KEEPK) {
      const float* d = dets + ((size_t)b * TOPK + p) * 16;
      float* o = out + ((size_t)b * KEEPK + slot) * 15;
#pragma unroll
      for (int c = 0; c < 15; ++c) o[c] = d[c];
      out[(size_t)B * KEEPK * 15 + (size_t)b * KEEPK + slot] = kept ? 1.0f : 0.0f;
    }
  }
}

extern "C" void kernel_launch(void* const* d_in, const int* in_sizes, int n_in,
                              void* d_out, int out_size, void* d_ws, size_t ws_size,
                              hipStream_t stream) {
  const float* cls    = (const float*)d_in[0];
  const float* obj    = (const float*)d_in[1];
  const float* bbox   = (const float*)d_in[2];
  const float* kps    = (const float*)d_in[3];
  const float* priors = (const float*)d_in[4];
  int N = in_sizes[4] / 4;
  int B = in_sizes[0] / N;
  if (N > MPAD) return;

  char* ws = (char*)d_ws;
  size_t off = 0;
  auto alloc = [&](size_t bytes) -> void* {
    void* p = ws + off;
    off += (bytes + 255) & ~(size_t)255;
    return p;
  };
  uint64_t* keys1  = (uint64_t*)alloc((size_t)B * MPAD * 8);
  float*    dets   = (float*)   alloc((size_t)B * TOPK * 16 * 4);
  float*    tscore = (float*)   alloc((size_t)B * TOPK * 4);
  uint64_t* mask   = (uint64_t*)alloc((size_t)B * NBLK * KROW * 8);
  if (off > ws_size) return;  // fail visibly rather than corrupt

  build_keys<<<dim3((MPAD + 255) / 256, B), 256, 0, stream>>>(cls, obj, keys1, N);
  bitonic_local_full<<<dim3(MPAD / 8192, B), 1024, 0, stream>>>(keys1);
  for (int k = 16384; k <= MPAD; k <<= 1) {
    for (int j = k >> 1; j >= 8192; j >>= 1)
      bitonic_global_pass<<<dim3(MPAD / 2 / 256, B), 256, 0, stream>>>(keys1, k, j);
    bitonic_local_finish<<<dim3(MPAD / 8192, B), 1024, 0, stream>>>(keys1, k);
  }
  gather_decode<<<dim3((TOPK + 255) / 256, B), 256, 0, stream>>>(keys1, bbox, kps, priors,
                                                                 dets, tscore, N);
  nms_mask<<<dim3(NBLK, NBLK, B), 64, 0, stream>>>(dets, mask);
  nms_scan_emit<<<B, 64, 0, stream>>>(mask, tscore, dets, (float*)d_out, B);
}

// Round 4
// 704.445 us; speedup vs baseline: 1.9241x; 1.9241x over previous
//
#include <hip/hip_runtime.h>
#include <stdint.h>

#pragma clang fp contract(off)   // match numpy: no FMA fusion in decode/IoU math

static constexpr int TOPK  = 5000;
static constexpr int KEEPK = 750;
static constexpr int MPAD  = 65536;   // >= N (33600), power of 2
static constexpr int NBLK  = (TOPK + 63) / 64;   // 79
static constexpr int KROW  = NBLK * 64;          // 5056 (padded mask row)
static constexpr int LDSW  = 5120;               // 80 rows of 64 words (stage pad)
static constexpr float TH  = 0.3f;    // strict '>' everywhere (f32 weak-typed 0.3)

__device__ __forceinline__ uint32_t key_of(float f) {
  uint32_t u = __float_as_uint(f);
  u = (u & 0x80000000u) ? ~u : (u | 0x80000000u);  // ascending-ordered uint
  return ~u;                                        // ascending key == descending float
}
__device__ __forceinline__ float val_of(uint32_t key) {
  uint32_t u = ~key;
  return (u & 0x80000000u) ? __uint_as_float(u ^ 0x80000000u) : __uint_as_float(~u);
}

// ---------------- stage 1: composite keys (score desc, index asc) ----------------
__global__ void build_keys(const float* __restrict__ cls, const float* __restrict__ obj,
                           uint64_t* __restrict__ keys, int N) {
  int b = blockIdx.y;
  int i = blockIdx.x * blockDim.x + threadIdx.x;
  if (i >= MPAD) return;
  uint64_t c = ~0ull;
  if (i < N) {
    size_t o = (size_t)b * N + i;
    float s = sqrtf(cls[o] * obj[o]);          // mul+sqrt: bit-exact vs np
    float m = (s > TH) ? s : -1.0f;            // strict > (jax weak-typed f32 0.3)
    c = ((uint64_t)key_of(m) << 32) | (uint32_t)i;
  }
  keys[(size_t)b * MPAD + i] = c;
}

// ---------------- bitonic sort (ascending) over MPAD per batch ----------------
__global__ __launch_bounds__(1024) void bitonic_local_full(uint64_t* __restrict__ keys) {
  __shared__ uint64_t sh[8192];
  int base = blockIdx.x * 8192;
  uint64_t* a = keys + (size_t)blockIdx.y * MPAD + base;
  for (int t = threadIdx.x; t < 8192; t += 1024) sh[t] = a[t];
  __syncthreads();
  for (int k = 2; k <= 8192; k <<= 1) {
    for (int j = k >> 1; j > 0; j >>= 1) {
      for (int t = threadIdx.x; t < 4096; t += 1024) {
        int i = ((t & ~(j - 1)) << 1) | (t & (j - 1));
        int l = i | j;
        bool asc = (((base + i) & k) == 0);
        uint64_t x = sh[i], y = sh[l];
        if ((x > y) == asc) { sh[i] = y; sh[l] = x; }
      }
      __syncthreads();
    }
  }
  for (int t = threadIdx.x; t < 8192; t += 1024) a[t] = sh[t];
}

__global__ void bitonic_global_pass(uint64_t* __restrict__ keys, int k, int j) {
  int b = blockIdx.y;
  int t = blockIdx.x * blockDim.x + threadIdx.x;  // t < MPAD/2
  uint64_t* a = keys + (size_t)b * MPAD;
  int i = ((t & ~(j - 1)) << 1) | (t & (j - 1));
  int l = i | j;
  bool asc = ((i & k) == 0);
  uint64_t x = a[i], y = a[l];
  if ((x > y) == asc) { a[i] = y; a[l] = x; }
}

__global__ __launch_bounds__(1024) void bitonic_local_finish(uint64_t* __restrict__ keys, int k) {
  __shared__ uint64_t sh[8192];
  int base = blockIdx.x * 8192;
  uint64_t* a = keys + (size_t)blockIdx.y * MPAD + base;
  for (int t = threadIdx.x; t < 8192; t += 1024) sh[t] = a[t];
  __syncthreads();
  for (int j = 4096; j > 0; j >>= 1) {
    for (int t = threadIdx.x; t < 4096; t += 1024) {
      int i = ((t & ~(j - 1)) << 1) | (t & (j - 1));
      int l = i | j;
      bool asc = (((base + i) & k) == 0);
      uint64_t x = sh[i], y = sh[l];
      if ((x > y) == asc) { sh[i] = y; sh[l] = x; }
    }
    __syncthreads();
  }
  for (int t = threadIdx.x; t < 8192; t += 1024) a[t] = sh[t];
}

// ---------------- stage 2: gather top-5000, decode boxes+kps ----------------
__global__ void gather_decode(const uint64_t* __restrict__ keys,
                              const float* __restrict__ bbox, const float* __restrict__ kps,
                              const float* __restrict__ priors,
                              float* __restrict__ dets, float* __restrict__ tscore, int N) {
  int b = blockIdx.y;
  int r = blockIdx.x * blockDim.x + threadIdx.x;
  if (r >= TOPK) return;
  uint64_t c = keys[(size_t)b * MPAD + r];
  uint32_t idx = (uint32_t)c;
  float score = val_of((uint32_t)(c >> 32));
  float4 pr = ((const float4*)priors)[idx];
  const float* bb = bbox + ((size_t)b * N + idx) * 4;
  float cx = pr.x + bb[0] * pr.z;
  float cy = pr.y + bb[1] * pr.w;
  float w = pr.z * expf(bb[2]);
  float h = pr.w * expf(bb[3]);
  float x1 = cx - w * 0.5f, y1 = cy - h * 0.5f;
  float* d = dets + ((size_t)b * TOPK + r) * 16;
  d[0] = x1; d[1] = y1; d[2] = x1 + w; d[3] = y1 + h;
  const float* kp = kps + ((size_t)b * N + idx) * 10;
#pragma unroll
  for (int q = 0; q < 5; ++q) {
    d[4 + 2 * q] = pr.x + kp[2 * q] * pr.z;
    d[5 + 2 * q] = pr.y + kp[2 * q + 1] * pr.w;
  }
  d[14] = score;
  tscore[(size_t)b * TOPK + r] = score;
}

// ---------------- stage 3: NMS bitmask, TRANSPOSED (target-major) ----------------
// Block (sbk, tbk, b), tbk >= sbk. Lane t = source item sbk*64+t computes bits over
// targets u in chunk tbk (only j>i pairs). Then a 64-ballot in-register transpose
// yields, for lane u = target item, the word "which sources in sbk suppress me",
// stored at tmask[(b,tbk)][sbk*64+u] (coalesced, gather-friendly in the scan).
__global__ __launch_bounds__(64) void nms_mask(const float* __restrict__ dets,
                                               uint64_t* __restrict__ tmask) {
  int sbk = blockIdx.x, tbk = blockIdx.y, b = blockIdx.z;
  if (tbk < sbk) return;
  __shared__ float4 tbox[64];
  int t = threadIdx.x;
  int j0 = tbk * 64;
  {
    int j = j0 + t;
    if (j < TOPK) {
      const float* dj = dets + ((size_t)b * TOPK + j) * 16;
      tbox[t] = make_float4(dj[0], dj[1], dj[2], dj[3]);
    } else tbox[t] = make_float4(0.f, 0.f, 0.f, 0.f);
  }
  __syncthreads();
  int i = sbk * 64 + t;
  uint64_t bits = 0;
  if (i < TOPK) {
    const float* di = dets + ((size_t)b * TOPK + i) * 16;
    float ix1 = di[0], iy1 = di[1], ix2 = di[2], iy2 = di[3];
    float iar = fmaxf(ix2 - ix1, 0.f) * fmaxf(iy2 - iy1, 0.f);
    int jmax = min(64, TOPK - j0);
    for (int u = 0; u < jmax; ++u) {
      int j = j0 + u;
      if (j <= i) continue;
      float4 bx = tbox[u];
      float xx1 = fmaxf(ix1, bx.x), yy1 = fmaxf(iy1, bx.y);
      float xx2 = fminf(ix2, bx.z), yy2 = fminf(iy2, bx.w);
      float ww = fmaxf(xx2 - xx1, 0.f), hh = fmaxf(yy2 - yy1, 0.f);
      float inter = ww * hh;
      float jar = fmaxf(bx.z - bx.x, 0.f) * fmaxf(bx.w - bx.y, 0.f);
      float iou = inter / (iar + jar - inter + 1e-12f);
      if (iou > TH) bits |= (1ull << u);       // strict > (f32 0.3)
    }
  }
  // transpose: word for target u = ballot over source lanes of bit u
  uint64_t tw = 0;
#pragma unroll
  for (int u = 0; u < 64; ++u) {
    uint64_t bal = __ballot((bits >> u) & 1ull);
    if (t == u) tw = bal;
  }
  tmask[((size_t)b * NBLK + tbk) * KROW + (size_t)(sbk * 64 + t)] = tw;
}

// ---------------- stage 4+5: prefetched greedy scan + fused top-750 emit ----------------
// One wave per batch. Chunk c's row block (tmask[(b,c)][0 .. (c+1)*64)) is staged
// into an LDS double-buffer via global_load_lds, issued one chunk AHEAD so the
// ~700-cycle L3 latency hides under the previous chunk's gather+closure.
// Per-lane transposed gather: no cross-lane reduce. Closure: 64-step ballot chain.
__global__ __launch_bounds__(64) void nms_scan_emit(const uint64_t* __restrict__ tmask,
                                                    const float* __restrict__ tscore,
                                                    const float* __restrict__ dets,
                                                    float* __restrict__ out, int B) {
  __shared__ uint64_t buf[2][LDSW];
  __shared__ uint64_t s_alive[NBLK];
  __shared__ int s_pref[NBLK + 1];
  int b = blockIdx.x;
  int lane = threadIdx.x;
  const uint64_t* mb = tmask + (size_t)b * NBLK * KROW;
  const float* sb = tscore + (size_t)b * TOPK;

  auto stage = [&](int c) {
    const uint64_t* src = mb + (size_t)c * KROW;
    int ni = (c + 2) >> 1;                       // ceil((c+1)/2) rows-pairs, 1KB each
    for (int k = 0; k < ni; ++k) {
      __builtin_amdgcn_global_load_lds(
          (__attribute__((address_space(1))) void*)(src + (size_t)k * 128 + lane * 2),
          (__attribute__((address_space(3))) void*)(&buf[c & 1][k * 128]),
          16, 0, 0);                             // lane i -> words k*128+2i,2i+1
    }
  };

  stage(0);
  for (int c = 0; c < NBLK; ++c) {
    asm volatile("s_waitcnt vmcnt(0)" ::: "memory");   // chunk c resident in LDS
    if (c + 1 < NBLK) stage(c + 1);                    // prefetch next (stays in flight)
    int p = c * 64 + lane;
    float s = (p < TOPK) ? sb[p] : -1.0f;
    const uint64_t* B0 = &buf[c & 1][0];
    uint64_t sup64 = 0;
    for (int cb = 0; cb < c; ++cb)                     // per-lane, pipelined LDS reads
      sup64 |= B0[cb * 64 + lane] & s_alive[cb];
    uint64_t dsup = B0[c * 64 + lane];                 // in-chunk suppressors (t<lane)
    bool sup = (sup64 != 0) || !(s > TH);
    uint64_t alive = 0;
    for (int t = 0; t < 64; ++t) {                     // serial greedy closure
      uint64_t lv = __ballot(!sup);
      if ((lv >> t) & 1ull) {                          // uniform branch
        alive |= (1ull << t);
        sup = sup || (((dsup >> t) & 1ull) != 0);
      }
    }
    if (lane == 0) s_alive[c] = alive;
  }

  // prefix sums of kept counts per chunk
  if (lane == 0) {
    int run = 0;
    for (int cb = 0; cb < NBLK; ++cb) { s_pref[cb] = run; run += __popcll(s_alive[cb]); }
    s_pref[NBLK] = run;
  }
  __syncthreads();
  int K = s_pref[NBLK];

  // top-750 of where(keep, score, -1) == [kept in position order] ++ [not-kept in
  // position order]  (tscore already desc with index-asc ties; -1 ties -> index asc)
  for (int cb = 0; cb < NBLK; ++cb) {
    int p = cb * 64 + lane;
    if (p >= TOPK) continue;
    uint64_t aw = s_alive[cb];
    int kept = (int)((aw >> lane) & 1ull);
    int within = __popcll(aw & ((1ull << lane) - 1ull));
    int rank = s_pref[cb] + within;                          // kept rank
    int slot = kept ? rank : (K + (p - s_pref[cb] - within)); // filler after all kept
    if (slot < KEEPK) {
      const float* d = dets + ((size_t)b * TOPK + p) * 16;
      float* o = out + ((size_t)b * KEEPK + slot) * 15;
#pragma unroll
      for (int ccol = 0; ccol < 15; ++ccol) o[ccol] = d[ccol];
      out[(size_t)B * KEEPK * 15 + (size_t)b * KEEPK + slot] = kept ? 1.0f : 0.0f;
    }
  }
}

extern "C" void kernel_launch(void* const* d_in, const int* in_sizes, int n_in,
                              void* d_out, int out_size, void* d_ws, size_t ws_size,
                              hipStream_t stream) {
  const float* cls    = (const float*)d_in[0];
  const float* obj    = (const float*)d_in[1];
  const float* bbox   = (const float*)d_in[2];
  const float* kps    = (const float*)d_in[3];
  const float* priors = (const float*)d_in[4];
  int N = in_sizes[4] / 4;
  int B = in_sizes[0] / N;
  if (N > MPAD) return;

  char* ws = (char*)d_ws;
  size_t off = 0;
  auto alloc = [&](size_t bytes) -> void* {
    void* p = ws + off;
    off += (bytes + 255) & ~(size_t)255;
    return p;
  };
  uint64_t* keys1  = (uint64_t*)alloc((size_t)B * MPAD * 8);
  float*    dets   = (float*)   alloc((size_t)B * TOPK * 16 * 4);
  float*    tscore = (float*)   alloc((size_t)B * TOPK * 4);
  uint64_t* tmask  = (uint64_t*)alloc((size_t)B * NBLK * KROW * 8 + 4096); // +stage overrun pad
  if (off > ws_size) return;  // fail visibly rather than corrupt

  build_keys<<<dim3((MPAD + 255) / 256, B), 256, 0, stream>>>(cls, obj, keys1, N);
  bitonic_local_full<<<dim3(MPAD / 8192, B), 1024, 0, stream>>>(keys1);
  for (int k = 16384; k <= MPAD; k <<= 1) {
    for (int j = k >> 1; j >= 8192; j >>= 1)
      bitonic_global_pass<<<dim3(MPAD / 2 / 256, B), 256, 0, stream>>>(keys1, k, j);
    bitonic_local_finish<<<dim3(MPAD / 8192, B), 1024, 0, stream>>>(keys1, k);
  }
  gather_decode<<<dim3((TOPK + 255) / 256, B), 256, 0, stream>>>(keys1, bbox, kps, priors,
                                                                 dets, tscore, N);
  nms_mask<<<dim3(NBLK, NBLK, B), 64, 0, stream>>>(dets, tmask);
  nms_scan_emit<<<B, 64, 0, stream>>>(tmask, tscore, dets, (float*)d_out, B);
}

// Round 5
// 666.671 us; speedup vs baseline: 2.0331x; 1.0567x over previous
//
#include <hip/hip_runtime.h>
#include <stdint.h>

#pragma clang fp contract(off)   // match numpy: no FMA fusion in decode/IoU math

static constexpr int TOPK  = 5000;
static constexpr int KEEPK = 750;
static constexpr int MPAD  = 65536;   // >= N (33600), power of 2
static constexpr int NBLK  = (TOPK + 63) / 64;   // 79
static constexpr int KROW  = NBLK * 64;          // 5056 (padded mask row)
static constexpr int LDSW  = 5120;               // 80 rows of 64 words (stage pad)
static constexpr float TH  = 0.3f;    // strict '>' everywhere (f32 weak-typed 0.3)

__device__ __forceinline__ uint32_t key_of(float f) {
  uint32_t u = __float_as_uint(f);
  u = (u & 0x80000000u) ? ~u : (u | 0x80000000u);  // ascending-ordered uint
  return ~u;                                        // ascending key == descending float
}
__device__ __forceinline__ float val_of(uint32_t key) {
  uint32_t u = ~key;
  return (u & 0x80000000u) ? __uint_as_float(u ^ 0x80000000u) : __uint_as_float(~u);
}

// ---------------- stage 1: composite keys (score desc, index asc) ----------------
__global__ void build_keys(const float* __restrict__ cls, const float* __restrict__ obj,
                           uint64_t* __restrict__ keys, int N) {
  int b = blockIdx.y;
  int i = blockIdx.x * blockDim.x + threadIdx.x;
  if (i >= MPAD) return;
  uint64_t c = ~0ull;
  if (i < N) {
    size_t o = (size_t)b * N + i;
    float s = sqrtf(cls[o] * obj[o]);          // mul+sqrt: bit-exact vs np
    float m = (s > TH) ? s : -1.0f;            // strict > (jax weak-typed f32 0.3)
    c = ((uint64_t)key_of(m) << 32) | (uint32_t)i;
  }
  keys[(size_t)b * MPAD + i] = c;
}

// ---------------- bitonic sort (ascending) over MPAD per batch ----------------
__global__ __launch_bounds__(1024) void bitonic_local_full(uint64_t* __restrict__ keys) {
  __shared__ uint64_t sh[8192];
  int base = blockIdx.x * 8192;
  uint64_t* a = keys + (size_t)blockIdx.y * MPAD + base;
  for (int t = threadIdx.x; t < 8192; t += 1024) sh[t] = a[t];
  __syncthreads();
  for (int k = 2; k <= 8192; k <<= 1) {
    for (int j = k >> 1; j > 0; j >>= 1) {
      for (int t = threadIdx.x; t < 4096; t += 1024) {
        int i = ((t & ~(j - 1)) << 1) | (t & (j - 1));
        int l = i | j;
        bool asc = (((base + i) & k) == 0);
        uint64_t x = sh[i], y = sh[l];
        if ((x > y) == asc) { sh[i] = y; sh[l] = x; }
      }
      __syncthreads();
    }
  }
  for (int t = threadIdx.x; t < 8192; t += 1024) a[t] = sh[t];
}

__global__ void bitonic_global_pass(uint64_t* __restrict__ keys, int k, int j) {
  int b = blockIdx.y;
  int t = blockIdx.x * blockDim.x + threadIdx.x;  // t < MPAD/2
  uint64_t* a = keys + (size_t)b * MPAD;
  int i = ((t & ~(j - 1)) << 1) | (t & (j - 1));
  int l = i | j;
  bool asc = ((i & k) == 0);
  uint64_t x = a[i], y = a[l];
  if ((x > y) == asc) { a[i] = y; a[l] = x; }
}

__global__ __launch_bounds__(1024) void bitonic_local_finish(uint64_t* __restrict__ keys, int k) {
  __shared__ uint64_t sh[8192];
  int base = blockIdx.x * 8192;
  uint64_t* a = keys + (size_t)blockIdx.y * MPAD + base;
  for (int t = threadIdx.x; t < 8192; t += 1024) sh[t] = a[t];
  __syncthreads();
  for (int j = 4096; j > 0; j >>= 1) {
    for (int t = threadIdx.x; t < 4096; t += 1024) {
      int i = ((t & ~(j - 1)) << 1) | (t & (j - 1));
      int l = i | j;
      bool asc = (((base + i) & k) == 0);
      uint64_t x = sh[i], y = sh[l];
      if ((x > y) == asc) { sh[i] = y; sh[l] = x; }
    }
    __syncthreads();
  }
  for (int t = threadIdx.x; t < 8192; t += 1024) a[t] = sh[t];
}

// ---------------- stage 2: gather top-5000, decode boxes+kps ----------------
__global__ void gather_decode(const uint64_t* __restrict__ keys,
                              const float* __restrict__ bbox, const float* __restrict__ kps,
                              const float* __restrict__ priors,
                              float* __restrict__ dets, float* __restrict__ tscore, int N) {
  int b = blockIdx.y;
  int r = blockIdx.x * blockDim.x + threadIdx.x;
  if (r >= TOPK) return;
  uint64_t c = keys[(size_t)b * MPAD + r];
  uint32_t idx = (uint32_t)c;
  float score = val_of((uint32_t)(c >> 32));
  float4 pr = ((const float4*)priors)[idx];
  const float* bb = bbox + ((size_t)b * N + idx) * 4;
  float cx = pr.x + bb[0] * pr.z;
  float cy = pr.y + bb[1] * pr.w;
  float w = pr.z * expf(bb[2]);
  float h = pr.w * expf(bb[3]);
  float x1 = cx - w * 0.5f, y1 = cy - h * 0.5f;
  float* d = dets + ((size_t)b * TOPK + r) * 16;
  d[0] = x1; d[1] = y1; d[2] = x1 + w; d[3] = y1 + h;
  const float* kp = kps + ((size_t)b * N + idx) * 10;
#pragma unroll
  for (int q = 0; q < 5; ++q) {
    d[4 + 2 * q] = pr.x + kp[2 * q] * pr.z;
    d[5 + 2 * q] = pr.y + kp[2 * q + 1] * pr.w;
  }
  d[14] = score;
  tscore[(size_t)b * TOPK + r] = score;
}

// ---------------- stage 3: NMS bitmask, TRANSPOSED (target-major) ----------------
__global__ __launch_bounds__(64) void nms_mask(const float* __restrict__ dets,
                                               uint64_t* __restrict__ tmask) {
  int sbk = blockIdx.x, tbk = blockIdx.y, b = blockIdx.z;
  if (tbk < sbk) return;
  __shared__ float4 tbox[64];
  int t = threadIdx.x;
  int j0 = tbk * 64;
  {
    int j = j0 + t;
    if (j < TOPK) {
      const float* dj = dets + ((size_t)b * TOPK + j) * 16;
      tbox[t] = make_float4(dj[0], dj[1], dj[2], dj[3]);
    } else tbox[t] = make_float4(0.f, 0.f, 0.f, 0.f);
  }
  __syncthreads();
  int i = sbk * 64 + t;
  uint64_t bits = 0;
  if (i < TOPK) {
    const float* di = dets + ((size_t)b * TOPK + i) * 16;
    float ix1 = di[0], iy1 = di[1], ix2 = di[2], iy2 = di[3];
    float iar = fmaxf(ix2 - ix1, 0.f) * fmaxf(iy2 - iy1, 0.f);
    int jmax = min(64, TOPK - j0);
    for (int u = 0; u < jmax; ++u) {
      int j = j0 + u;
      if (j <= i) continue;
      float4 bx = tbox[u];
      float xx1 = fmaxf(ix1, bx.x), yy1 = fmaxf(iy1, bx.y);
      float xx2 = fminf(ix2, bx.z), yy2 = fminf(iy2, bx.w);
      float ww = fmaxf(xx2 - xx1, 0.f), hh = fmaxf(yy2 - yy1, 0.f);
      float inter = ww * hh;
      float jar = fmaxf(bx.z - bx.x, 0.f) * fmaxf(bx.w - bx.y, 0.f);
      float iou = inter / (iar + jar - inter + 1e-12f);
      if (iou > TH) bits |= (1ull << u);       // strict > (f32 0.3)
    }
  }
  // transpose: word for target u = ballot over source lanes of bit u
  uint64_t tw = 0;
#pragma unroll
  for (int u = 0; u < 64; ++u) {
    uint64_t bal = __ballot((bits >> u) & 1ull);
    if (t == u) tw = bal;
  }
  tmask[((size_t)b * NBLK + tbk) * KROW + (size_t)(sbk * 64 + t)] = tw;
}

// ---------------- stage 4+5: prefetched scan (batched gather) + fused emit ----------------
// One wave per batch. Per chunk c: mask rows staged ahead via global_load_lds
// (double-buffer); gather is EXPLICITLY 16-way unrolled so the 32 ds_reads issue
// back-to-back (round-4 rolled loop serialized at ~120cyc/read = 12k cyc/chunk);
// closure iterates only over surviving candidates (ffsll over ballot).
__global__ __launch_bounds__(64) void nms_scan_emit(const uint64_t* __restrict__ tmask,
                                                    const float* __restrict__ tscore,
                                                    const float* __restrict__ dets,
                                                    float* __restrict__ out, int B) {
  __shared__ uint64_t buf[2][LDSW];
  __shared__ float s_scores[LDSW];
  __shared__ uint64_t s_alive[96];
  __shared__ int s_pref[NBLK + 1];
  int b = blockIdx.x;
  int lane = threadIdx.x;
  const uint64_t* mb = tmask + (size_t)b * NBLK * KROW;
  const float* sb = tscore + (size_t)b * TOPK;

  // pre-zero alive history (lets gather run full 16-batches over garbage rows)
  s_alive[lane] = 0;
  if (lane < 32) s_alive[64 + lane] = 0;

  auto stage = [&](int c) {
    const uint64_t* src = mb + (size_t)c * KROW;
    int ni = (c + 2) >> 1;                       // ceil((c+1)/2) row-pairs, 1KB each
    for (int k = 0; k < ni; ++k) {
      __builtin_amdgcn_global_load_lds(
          (__attribute__((address_space(1))) void*)(src + (size_t)k * 128 + lane * 2),
          (__attribute__((address_space(3))) void*)(&buf[c & 1][k * 128]),
          16, 0, 0);                             // lane i -> words k*128+2i,2i+1
    }
  };
  // stage all 5000 scores to LDS once (keeps per-chunk loop free of global loads,
  // whose compiler-inserted vmcnt(0) before use would drain the mask prefetch)
  for (int k = 0; k < 20; ++k) {
    __builtin_amdgcn_global_load_lds(
        (__attribute__((address_space(1))) void*)(sb + k * 256 + lane * 4),
        (__attribute__((address_space(3))) void*)(&s_scores[k * 256]),
        16, 0, 0);
  }
  stage(0);
  __syncthreads();

  for (int c = 0; c < NBLK; ++c) {
    asm volatile("s_waitcnt vmcnt(0)" ::: "memory");   // chunk c resident in LDS
    if (c + 1 < NBLK) stage(c + 1);                    // prefetch next (stays in flight)
    const uint64_t* B0 = &buf[c & 1][0];
    uint64_t dsup = B0[c * 64 + lane];                 // in-chunk suppressors (t<lane)
    // gather: OR of (mask word & alive word) over prior chunks, 16-way batched.
    // rows >= c are staged-garbage or stale but masked by s_alive==0.
    uint64_t sup64 = 0;
    int nb = (c + 15) & ~15;
    for (int cb = 0; cb < nb; cb += 16) {
      uint64_t m0  = B0[(cb +  0) * 64 + lane], a0  = s_alive[cb +  0];
      uint64_t m1  = B0[(cb +  1) * 64 + lane], a1  = s_alive[cb +  1];
      uint64_t m2  = B0[(cb +  2) * 64 + lane], a2  = s_alive[cb +  2];
      uint64_t m3  = B0[(cb +  3) * 64 + lane], a3  = s_alive[cb +  3];
      uint64_t m4  = B0[(cb +  4) * 64 + lane], a4  = s_alive[cb +  4];
      uint64_t m5  = B0[(cb +  5) * 64 + lane], a5  = s_alive[cb +  5];
      uint64_t m6  = B0[(cb +  6) * 64 + lane], a6  = s_alive[cb +  6];
      uint64_t m7  = B0[(cb +  7) * 64 + lane], a7  = s_alive[cb +  7];
      uint64_t m8  = B0[(cb +  8) * 64 + lane], a8  = s_alive[cb +  8];
      uint64_t m9  = B0[(cb +  9) * 64 + lane], a9  = s_alive[cb +  9];
      uint64_t m10 = B0[(cb + 10) * 64 + lane], a10 = s_alive[cb + 10];
      uint64_t m11 = B0[(cb + 11) * 64 + lane], a11 = s_alive[cb + 11];
      uint64_t m12 = B0[(cb + 12) * 64 + lane], a12 = s_alive[cb + 12];
      uint64_t m13 = B0[(cb + 13) * 64 + lane], a13 = s_alive[cb + 13];
      uint64_t m14 = B0[(cb + 14) * 64 + lane], a14 = s_alive[cb + 14];
      uint64_t m15 = B0[(cb + 15) * 64 + lane], a15 = s_alive[cb + 15];
      uint64_t r0 = (m0 & a0) | (m1 & a1) | (m2 & a2) | (m3 & a3);
      uint64_t r1 = (m4 & a4) | (m5 & a5) | (m6 & a6) | (m7 & a7);
      uint64_t r2 = (m8 & a8) | (m9 & a9) | (m10 & a10) | (m11 & a11);
      uint64_t r3 = (m12 & a12) | (m13 & a13) | (m14 & a14) | (m15 & a15);
      sup64 |= (r0 | r1) | (r2 | r3);
    }
    int p = c * 64 + lane;
    float s = s_scores[p];                             // LDS (staged in prologue)
    bool sup = (sup64 != 0) || !(p < TOPK && s > TH);
    // greedy closure: iterate only surviving candidates
    uint64_t alive = 0;
    uint64_t cand = __ballot(!sup);
    while (cand) {
      int t = __ffsll((unsigned long long)cand) - 1;
      alive |= (1ull << t);
      sup = sup || (((dsup >> t) & 1ull) != 0);
      uint64_t above = ~(((1ull << t) << 1) - 1ull);   // bits > t (t=63 -> 0)
      cand = __ballot(!sup) & above;
    }
    if (lane == 0) s_alive[c] = alive;
    __syncthreads();
  }

  // prefix sums of kept counts per chunk
  if (lane == 0) {
    int run = 0;
    for (int cb = 0; cb < NBLK; ++cb) { s_pref[cb] = run; run += __popcll(s_alive[cb]); }
    s_pref[NBLK] = run;
  }
  __syncthreads();
  int K = s_pref[NBLK];

  // top-750 of where(keep, score, -1) == [kept in position order] ++ [not-kept in
  // position order]  (tscore already desc with index-asc ties; -1 ties -> index asc)
  for (int cb = 0; cb < NBLK; ++cb) {
    int p = cb * 64 + lane;
    if (p >= TOPK) continue;
    uint64_t aw = s_alive[cb];
    int kept = (int)((aw >> lane) & 1ull);
    int within = __popcll(aw & ((1ull << lane) - 1ull));
    int rank = s_pref[cb] + within;                          // kept rank
    int slot = kept ? rank : (K + (p - s_pref[cb] - within)); // filler after all kept
    if (slot < KEEPK) {
      const float* d = dets + ((size_t)b * TOPK + p) * 16;
      float* o = out + ((size_t)b * KEEPK + slot) * 15;
#pragma unroll
      for (int ccol = 0; ccol < 15; ++ccol) o[ccol] = d[ccol];
      out[(size_t)B * KEEPK * 15 + (size_t)b * KEEPK + slot] = kept ? 1.0f : 0.0f;
    }
  }
}

extern "C" void kernel_launch(void* const* d_in, const int* in_sizes, int n_in,
                              void* d_out, int out_size, void* d_ws, size_t ws_size,
                              hipStream_t stream) {
  const float* cls    = (const float*)d_in[0];
  const float* obj    = (const float*)d_in[1];
  const float* bbox   = (const float*)d_in[2];
  const float* kps    = (const float*)d_in[3];
  const float* priors = (const float*)d_in[4];
  int N = in_sizes[4] / 4;
  int B = in_sizes[0] / N;
  if (N > MPAD) return;

  char* ws = (char*)d_ws;
  size_t off = 0;
  auto alloc = [&](size_t bytes) -> void* {
    void* p = ws + off;
    off += (bytes + 255) & ~(size_t)255;
    return p;
  };
  uint64_t* keys1  = (uint64_t*)alloc((size_t)B * MPAD * 8);
  float*    dets   = (float*)   alloc((size_t)B * TOPK * 16 * 4);
  float*    tscore = (float*)   alloc((size_t)B * TOPK * 4);
  uint64_t* tmask  = (uint64_t*)alloc((size_t)B * NBLK * KROW * 8 + 4096); // +stage overrun pad
  if (off > ws_size) return;  // fail visibly rather than corrupt

  build_keys<<<dim3((MPAD + 255) / 256, B), 256, 0, stream>>>(cls, obj, keys1, N);
  bitonic_local_full<<<dim3(MPAD / 8192, B), 1024, 0, stream>>>(keys1);
  for (int k = 16384; k <= MPAD; k <<= 1) {
    for (int j = k >> 1; j >= 8192; j >>= 1)
      bitonic_global_pass<<<dim3(MPAD / 2 / 256, B), 256, 0, stream>>>(keys1, k, j);
    bitonic_local_finish<<<dim3(MPAD / 8192, B), 1024, 0, stream>>>(keys1, k);
  }
  gather_decode<<<dim3((TOPK + 255) / 256, B), 256, 0, stream>>>(keys1, bbox, kps, priors,
                                                                 dets, tscore, N);
  nms_mask<<<dim3(NBLK, NBLK, B), 64, 0, stream>>>(dets, tmask);
  nms_scan_emit<<<B, 64, 0, stream>>>(tmask, tscore, dets, (float*)d_out, B);
}

// Round 6
// 627.311 us; speedup vs baseline: 2.1607x; 1.0627x over previous
//
#include <hip/hip_runtime.h>
#include <stdint.h>

#pragma clang fp contract(off)   // match numpy: no FMA fusion in decode/IoU math

static constexpr int TOPK  = 5000;
static constexpr int KEEPK = 750;
static constexpr int MPAD  = 65536;   // >= N (33600), power of 2
static constexpr int NBLK  = (TOPK + 63) / 64;   // 79
static constexpr int KROW  = NBLK * 64;          // 5056 (padded mask row)
static constexpr int LDSW  = 5120;               // 80 rows of 64 words (stage pad)
static constexpr float TH  = 0.3f;    // strict '>' everywhere (f32 weak-typed 0.3)

__device__ __forceinline__ uint32_t key_of(float f) {
  uint32_t u = __float_as_uint(f);
  u = (u & 0x80000000u) ? ~u : (u | 0x80000000u);  // ascending-ordered uint
  return ~u;                                        // ascending key == descending float
}
__device__ __forceinline__ float val_of(uint32_t key) {
  uint32_t u = ~key;
  return (u & 0x80000000u) ? __uint_as_float(u ^ 0x80000000u) : __uint_as_float(~u);
}

// ---------------- stage 1: composite keys (score desc, index asc) ----------------
__global__ void build_keys(const float* __restrict__ cls, const float* __restrict__ obj,
                           uint64_t* __restrict__ keys, int N) {
  int b = blockIdx.y;
  int i = blockIdx.x * blockDim.x + threadIdx.x;
  if (i >= MPAD) return;
  uint64_t c = ~0ull;
  if (i < N) {
    size_t o = (size_t)b * N + i;
    float s = sqrtf(cls[o] * obj[o]);          // mul+sqrt: bit-exact vs np
    float m = (s > TH) ? s : -1.0f;            // strict > (jax weak-typed f32 0.3)
    c = ((uint64_t)key_of(m) << 32) | (uint32_t)i;
  }
  keys[(size_t)b * MPAD + i] = c;
}

// ---------------- local bitonic: sorts each 8192-chunk, alternating asc/desc ----------------
__global__ __launch_bounds__(1024) void bitonic_local_full(uint64_t* __restrict__ keys) {
  __shared__ uint64_t sh[8192];
  int base = blockIdx.x * 8192;
  uint64_t* a = keys + (size_t)blockIdx.y * MPAD + base;
  for (int t = threadIdx.x; t < 8192; t += 1024) sh[t] = a[t];
  __syncthreads();
  for (int k = 2; k <= 8192; k <<= 1) {
    for (int j = k >> 1; j > 0; j >>= 1) {
      for (int t = threadIdx.x; t < 4096; t += 1024) {
        int i = ((t & ~(j - 1)) << 1) | (t & (j - 1));
        int l = i | j;
        bool asc = (((base + i) & k) == 0);
        uint64_t x = sh[i], y = sh[l];
        if ((x > y) == asc) { sh[i] = y; sh[l] = x; }
      }
      __syncthreads();
    }
  }
  for (int t = threadIdx.x; t < 8192; t += 1024) a[t] = sh[t];
}

// ---------------- merge-prune: keep smallest 8192 of (asc, desc) chunk pair ----------------
// src chunk 2m is ascending, 2m+1 descending (alternation from local_full / prior round).
// min(A[i], Bdesc[i]) = min(Aasc[i], Basc[L-1-i]) -> smallest-L multiset, bitonic sequence;
// 13 uniform-direction finish levels sort it (asc iff m even -> alternation preserved).
__global__ __launch_bounds__(1024) void merge_prune(const uint64_t* __restrict__ src,
                                                    uint64_t* __restrict__ dst) {
  __shared__ uint64_t sh[8192];
  int m = blockIdx.x, b = blockIdx.y;
  const uint64_t* A  = src + ((size_t)b * gridDim.x * 2 + 2 * m) * 8192;
  const uint64_t* Bp = A + 8192;
  for (int t = threadIdx.x; t < 8192; t += 1024) {
    uint64_t x = A[t], y = Bp[t];
    sh[t] = x < y ? x : y;
  }
  __syncthreads();
  bool asc = ((m & 1) == 0);
  for (int j = 4096; j > 0; j >>= 1) {
    for (int t = threadIdx.x; t < 4096; t += 1024) {
      int i = ((t & ~(j - 1)) << 1) | (t & (j - 1));
      int l = i | j;
      uint64_t x = sh[i], y = sh[l];
      if ((x > y) == asc) { sh[i] = y; sh[l] = x; }
    }
    __syncthreads();
  }
  uint64_t* D = dst + ((size_t)b * gridDim.x + m) * 8192;
  for (int t = threadIdx.x; t < 8192; t += 1024) D[t] = sh[t];
}

// ---------------- stage 2: gather top-5000, decode boxes+kps ----------------
__global__ void gather_decode(const uint64_t* __restrict__ keys,
                              const float* __restrict__ bbox, const float* __restrict__ kps,
                              const float* __restrict__ priors,
                              float* __restrict__ dets, float* __restrict__ tscore, int N) {
  int b = blockIdx.y;
  int r = blockIdx.x * blockDim.x + threadIdx.x;
  if (r >= TOPK) return;
  uint64_t c = keys[(size_t)b * 8192 + r];
  uint32_t idx = (uint32_t)c;
  float score = val_of((uint32_t)(c >> 32));
  float4 pr = ((const float4*)priors)[idx];
  const float* bb = bbox + ((size_t)b * N + idx) * 4;
  float cx = pr.x + bb[0] * pr.z;
  float cy = pr.y + bb[1] * pr.w;
  float w = pr.z * expf(bb[2]);
  float h = pr.w * expf(bb[3]);
  float x1 = cx - w * 0.5f, y1 = cy - h * 0.5f;
  float* d = dets + ((size_t)b * TOPK + r) * 16;
  d[0] = x1; d[1] = y1; d[2] = x1 + w; d[3] = y1 + h;
  const float* kp = kps + ((size_t)b * N + idx) * 10;
#pragma unroll
  for (int q = 0; q < 5; ++q) {
    d[4 + 2 * q] = pr.x + kp[2 * q] * pr.z;
    d[5 + 2 * q] = pr.y + kp[2 * q + 1] * pr.w;
  }
  d[14] = score;
  tscore[(size_t)b * TOPK + r] = score;
}

// ---------------- stage 3: NMS bitmask, transposed + diag kill-words ----------------
__global__ __launch_bounds__(64) void nms_mask(const float* __restrict__ dets,
                                               uint64_t* __restrict__ tmask,
                                               uint64_t* __restrict__ diag) {
  int sbk = blockIdx.x, tbk = blockIdx.y, b = blockIdx.z;
  if (tbk < sbk) return;
  __shared__ float4 tbox[64];
  int t = threadIdx.x;
  int j0 = tbk * 64;
  {
    int j = j0 + t;
    if (j < TOPK) {
      const float* dj = dets + ((size_t)b * TOPK + j) * 16;
      tbox[t] = make_float4(dj[0], dj[1], dj[2], dj[3]);
    } else tbox[t] = make_float4(0.f, 0.f, 0.f, 0.f);
  }
  __syncthreads();
  int i = sbk * 64 + t;
  uint64_t bits = 0;
  if (i < TOPK) {
    const float* di = dets + ((size_t)b * TOPK + i) * 16;
    float ix1 = di[0], iy1 = di[1], ix2 = di[2], iy2 = di[3];
    float iar = fmaxf(ix2 - ix1, 0.f) * fmaxf(iy2 - iy1, 0.f);
    int jmax = min(64, TOPK - j0);
    for (int u = 0; u < jmax; ++u) {
      int j = j0 + u;
      if (j <= i) continue;
      float4 bx = tbox[u];
      float xx1 = fmaxf(ix1, bx.x), yy1 = fmaxf(iy1, bx.y);
      float xx2 = fminf(ix2, bx.z), yy2 = fminf(iy2, bx.w);
      float ww = fmaxf(xx2 - xx1, 0.f), hh = fmaxf(yy2 - yy1, 0.f);
      float inter = ww * hh;
      float jar = fmaxf(bx.z - bx.x, 0.f) * fmaxf(bx.w - bx.y, 0.f);
      float iou = inter / (iar + jar - inter + 1e-12f);
      if (iou > TH) bits |= (1ull << u);       // strict > (f32 0.3)
    }
  }
  // in-chunk kill words for the scalar closure (source-major, bits only > t)
  if (sbk == tbk) diag[((size_t)b * NBLK + sbk) * 64 + t] = bits;
  // transpose: word for target u = ballot over source lanes of bit u
  uint64_t tw = 0;
#pragma unroll
  for (int u = 0; u < 64; ++u) {
    uint64_t bal = __ballot((bits >> u) & 1ull);
    if (t == u) tw = bal;
  }
  tmask[((size_t)b * NBLK + tbk) * KROW + (size_t)(sbk * 64 + t)] = tw;
}

// ---------------- stage 4+5: prefetched scan + SALU closure + fused emit ----------------
// One wave per batch. Mask rows double-buffered in LDS (global_load_lds, prefetch 1
// chunk ahead); gather explicitly 16-way batched; greedy closure runs 64 unrolled
// BRANCHLESS scalar steps (readlane kill-word + SALU chain, ~5cyc/step) replacing
// the ~9k-cyc ballot loop (round-5 lesson: most items survive NMS on this data).
__global__ __launch_bounds__(64) void nms_scan_emit(const uint64_t* __restrict__ tmask,
                                                    const uint64_t* __restrict__ diag,
                                                    const float* __restrict__ tscore,
                                                    const float* __restrict__ dets,
                                                    float* __restrict__ out, int B) {
  __shared__ uint64_t buf[2][LDSW];
  __shared__ uint64_t s_diag[LDSW];
  __shared__ float s_scores[LDSW];
  __shared__ uint64_t s_alive[96];
  __shared__ int s_pref[NBLK + 1];
  int b = blockIdx.x;
  int lane = threadIdx.x;
  const uint64_t* mb = tmask + (size_t)b * NBLK * KROW;
  const float* sb = tscore + (size_t)b * TOPK;
  const uint64_t* db = diag + (size_t)b * NBLK * 64;

  // pre-zero alive history (lets gather run full 16-batches over garbage rows)
  s_alive[lane] = 0;
  if (lane < 32) s_alive[64 + lane] = 0;

  auto stage = [&](int c) {
    const uint64_t* src = mb + (size_t)c * KROW;
    int ni = (c + 2) >> 1;                       // ceil((c+1)/2) row-pairs, 1KB each
    for (int k = 0; k < ni; ++k) {
      __builtin_amdgcn_global_load_lds(
          (__attribute__((address_space(1))) void*)(src + (size_t)k * 128 + lane * 2),
          (__attribute__((address_space(3))) void*)(&buf[c & 1][k * 128]),
          16, 0, 0);                             // lane i -> words k*128+2i,2i+1
    }
  };
  // prologue: stage scores (20KB) and diag kill-words (40KB) once; no per-chunk
  // global loads -> no compiler vmcnt(0) draining the mask prefetch.
  for (int k = 0; k < 20; ++k) {
    __builtin_amdgcn_global_load_lds(
        (__attribute__((address_space(1))) void*)(sb + k * 256 + lane * 4),
        (__attribute__((address_space(3))) void*)(&s_scores[k * 256]),
        16, 0, 0);
  }
  for (int k = 0; k < 40; ++k) {
    __builtin_amdgcn_global_load_lds(
        (__attribute__((address_space(1))) void*)(db + (size_t)k * 128 + lane * 2),
        (__attribute__((address_space(3))) void*)(&s_diag[k * 128]),
        16, 0, 0);
  }
  stage(0);
  __syncthreads();

  for (int c = 0; c < NBLK; ++c) {
    asm volatile("s_waitcnt vmcnt(0)" ::: "memory");   // chunk c (+prologue) resident
    if (c + 1 < NBLK) stage(c + 1);                    // prefetch next (stays in flight)
    const uint64_t* B0 = &buf[c & 1][0];
    // gather: OR of (mask word & alive word) over prior chunks, 16-way batched.
    // rows >= c are staged-garbage or stale but masked by s_alive==0.
    uint64_t sup64 = 0;
    int nb = (c + 15) & ~15;
    for (int cb = 0; cb < nb; cb += 16) {
      uint64_t m0  = B0[(cb +  0) * 64 + lane], a0  = s_alive[cb +  0];
      uint64_t m1  = B0[(cb +  1) * 64 + lane], a1  = s_alive[cb +  1];
      uint64_t m2  = B0[(cb +  2) * 64 + lane], a2  = s_alive[cb +  2];
      uint64_t m3  = B0[(cb +  3) * 64 + lane], a3  = s_alive[cb +  3];
      uint64_t m4  = B0[(cb +  4) * 64 + lane], a4  = s_alive[cb +  4];
      uint64_t m5  = B0[(cb +  5) * 64 + lane], a5  = s_alive[cb +  5];
      uint64_t m6  = B0[(cb +  6) * 64 + lane], a6  = s_alive[cb +  6];
      uint64_t m7  = B0[(cb +  7) * 64 + lane], a7  = s_alive[cb +  7];
      uint64_t m8  = B0[(cb +  8) * 64 + lane], a8  = s_alive[cb +  8];
      uint64_t m9  = B0[(cb +  9) * 64 + lane], a9  = s_alive[cb +  9];
      uint64_t m10 = B0[(cb + 10) * 64 + lane], a10 = s_alive[cb + 10];
      uint64_t m11 = B0[(cb + 11) * 64 + lane], a11 = s_alive[cb + 11];
      uint64_t m12 = B0[(cb + 12) * 64 + lane], a12 = s_alive[cb + 12];
      uint64_t m13 = B0[(cb + 13) * 64 + lane], a13 = s_alive[cb + 13];
      uint64_t m14 = B0[(cb + 14) * 64 + lane], a14 = s_alive[cb + 14];
      uint64_t m15 = B0[(cb + 15) * 64 + lane], a15 = s_alive[cb + 15];
      uint64_t r0 = (m0 & a0) | (m1 & a1) | (m2 & a2) | (m3 & a3);
      uint64_t r1 = (m4 & a4) | (m5 & a5) | (m6 & a6) | (m7 & a7);
      uint64_t r2 = (m8 & a8) | (m9 & a9) | (m10 & a10) | (m11 & a11);
      uint64_t r3 = (m12 & a12) | (m13 & a13) | (m14 & a14) | (m15 & a15);
      sup64 |= (r0 | r1) | (r2 | r3);
    }
    int p = c * 64 + lane;
    float s = s_scores[p];
    bool sup = (sup64 != 0) || !(p < TOPK && s > TH);
    uint64_t avail = __ballot(!sup);                   // uniform candidate set
    uint64_t dreg = s_diag[c * 64 + lane];             // lane t holds kill-word of t
    uint32_t dlo = (uint32_t)dreg, dhi = (uint32_t)(dreg >> 32);
    // branchless scalar greedy closure: 64 unrolled steps, pure SALU + readlane
    uint64_t alive = 0;
#pragma unroll
    for (int t = 0; t < 64; ++t) {
      uint64_t kill = ((uint64_t)__builtin_amdgcn_readlane(dhi, t) << 32)
                    | (uint64_t)__builtin_amdgcn_readlane(dlo, t);
      uint64_t take = (avail >> t) & 1ull;
      alive |= take << t;
      avail &= ~(kill & (0ull - take));
    }
    if (lane == 0) s_alive[c] = alive;
    __syncthreads();
  }

  // prefix sums of kept counts per chunk
  if (lane == 0) {
    int run = 0;
    for (int cb = 0; cb < NBLK; ++cb) { s_pref[cb] = run; run += __popcll(s_alive[cb]); }
    s_pref[NBLK] = run;
  }
  __syncthreads();
  int K = s_pref[NBLK];

  // top-750 of where(keep, score, -1) == [kept in position order] ++ [not-kept in
  // position order]  (tscore already desc with index-asc ties; -1 ties -> index asc)
  for (int cb = 0; cb < NBLK; ++cb) {
    int p = cb * 64 + lane;
    if (p >= TOPK) continue;
    uint64_t aw = s_alive[cb];
    int kept = (int)((aw >> lane) & 1ull);
    int within = __popcll(aw & ((1ull << lane) - 1ull));
    int rank = s_pref[cb] + within;                          // kept rank
    int slot = kept ? rank : (K + (p - s_pref[cb] - within)); // filler after all kept
    if (slot < KEEPK) {
      const float* d = dets + ((size_t)b * TOPK + p) * 16;
      float* o = out + ((size_t)b * KEEPK + slot) * 15;
#pragma unroll
      for (int ccol = 0; ccol < 15; ++ccol) o[ccol] = d[ccol];
      out[(size_t)B * KEEPK * 15 + (size_t)b * KEEPK + slot] = kept ? 1.0f : 0.0f;
    }
  }
}

extern "C" void kernel_launch(void* const* d_in, const int* in_sizes, int n_in,
                              void* d_out, int out_size, void* d_ws, size_t ws_size,
                              hipStream_t stream) {
  const float* cls    = (const float*)d_in[0];
  const float* obj    = (const float*)d_in[1];
  const float* bbox   = (const float*)d_in[2];
  const float* kps    = (const float*)d_in[3];
  const float* priors = (const float*)d_in[4];
  int N = in_sizes[4] / 4;
  int B = in_sizes[0] / N;
  if (N > MPAD) return;

  char* ws = (char*)d_ws;
  size_t off = 0;
  auto alloc = [&](size_t bytes) -> void* {
    void* p = ws + off;
    off += (bytes + 255) & ~(size_t)255;
    return p;
  };
  uint64_t* keys1  = (uint64_t*)alloc((size_t)B * MPAD * 8);
  float*    dets   = (float*)   alloc((size_t)B * TOPK * 16 * 4);
  float*    tscore = (float*)   alloc((size_t)B * TOPK * 4 + 4096);     // + stage pad
  uint64_t* diag   = (uint64_t*)alloc((size_t)B * NBLK * 64 * 8 + 4096); // + stage pad
  uint64_t* tmask  = (uint64_t*)alloc((size_t)B * NBLK * KROW * 8 + 4096);
  if (off > ws_size) return;  // fail visibly rather than corrupt
  // merge buffers alias tmask (lifetimes disjoint: sort completes before nms_mask)
  uint64_t* keys2 = tmask;                       // B * 4 * 8192
  uint64_t* keys3 = keys2 + (size_t)B * 4 * 8192;
  uint64_t* keys4 = keys3 + (size_t)B * 2 * 8192;

  build_keys<<<dim3((MPAD + 255) / 256, B), 256, 0, stream>>>(cls, obj, keys1, N);
  bitonic_local_full<<<dim3(MPAD / 8192, B), 1024, 0, stream>>>(keys1);
  merge_prune<<<dim3(4, B), 1024, 0, stream>>>(keys1, keys2);
  merge_prune<<<dim3(2, B), 1024, 0, stream>>>(keys2, keys3);
  merge_prune<<<dim3(1, B), 1024, 0, stream>>>(keys3, keys4);
  gather_decode<<<dim3((TOPK + 255) / 256, B), 256, 0, stream>>>(keys4, bbox, kps, priors,
                                                                 dets, tscore, N);
  nms_mask<<<dim3(NBLK, NBLK, B), 64, 0, stream>>>(dets, tmask, diag);
  nms_scan_emit<<<B, 64, 0, stream>>>(tmask, diag, tscore, dets, (float*)d_out, B);
}